// Round 4
// baseline (96.152 us; speedup 1.0000x reference)
//
#include <hip/hip_runtime.h>
#include <math.h>

#define EC 32
#define BLOCK 256
#define PPT 2   // points per thread

typedef float fvec4 __attribute__((ext_vector_type(4)));

__global__ __launch_bounds__(BLOCK) void ldif_fused_kernel(
    const float* __restrict__ pts,
    const fvec4* __restrict__ act,      // (EC, N) of float4
    const float* __restrict__ dists,
    const float* __restrict__ constants,
    const float* __restrict__ centers,
    const float* __restrict__ radii,
    const float* __restrict__ rotations,
    fvec4* __restrict__ out,
    float* __restrict__ penout,         // &out_flat[4*n]
    float* __restrict__ partials,
    unsigned int* __restrict__ counter,
    int n, int nblocks) {
    // params per component e (3 x float4), computed redundantly per-block:
    //  p0 = (cx, cy, cz, log2|c|)
    //  p1 = (Axx, Ayy, Azz, Axy)   A = -0.5*log2(e)*inv_cov, off-diag doubled
    //  p2 = (Axz, Ayz, 0, 0)
    __shared__ float4 sp[EC * 3];
    __shared__ float sred[4];
    __shared__ double rd[BLOCK];
    __shared__ int sdone;

    const int tid = threadIdx.x;
    if (tid < EC) {
        int e = tid;
        float r = fabsf(radii[e]);
        float dinv = 1.0f / (r + 1e-8f);
        float rx = rotations[3 * e + 0], ry = rotations[3 * e + 1], rz = rotations[3 * e + 2];
        float cx = cosf(rx), cy = cosf(ry), cz = cosf(rz);
        float sx = sinf(rx), sy = sinf(ry), sz = sinf(rz);
        float R00 = cz * cy, R01 = cz * sy * sx - sz * cx, R02 = cz * sy * cx + sz * sx;
        float R10 = sz * cy, R11 = sz * sy * sx + cz * cx, R12 = sz * sy * cx - cz * sx;
        float R20 = -sy,     R21 = cy * sx,                R22 = cy * cx;
        float ic00 = dinv * (R00 * R00 + R01 * R01 + R02 * R02);
        float ic11 = dinv * (R10 * R10 + R11 * R11 + R12 * R12);
        float ic22 = dinv * (R20 * R20 + R21 * R21 + R22 * R22);
        float ic01 = dinv * (R00 * R10 + R01 * R11 + R02 * R12);
        float ic02 = dinv * (R00 * R20 + R01 * R21 + R02 * R22);
        float ic12 = dinv * (R10 * R20 + R11 * R21 + R12 * R22);
        const float NH = -0.72134752044f;  // -0.5 * log2(e)
        float lc = log2f(fabsf(constants[e]));
        sp[3 * e + 0] = make_float4(centers[3 * e + 0], centers[3 * e + 1], centers[3 * e + 2], lc);
        sp[3 * e + 1] = make_float4(NH * ic00, NH * ic11, NH * ic22, 2.0f * NH * ic01);
        sp[3 * e + 2] = make_float4(2.0f * NH * ic02, 2.0f * NH * ic12, 0.0f, 0.0f);
    }
    __syncthreads();

    const long long i0 = (long long)blockIdx.x * (BLOCK * PPT) + tid;
    const long long i1 = i0 + BLOCK;
    const bool v1 = (i1 < n);
    const long long iq = v1 ? i1 : i0;

    float pen = 0.0f;
    {
        const float LOG2E = 1.44269504f;
        float pxp = __builtin_nontemporal_load(&pts[3 * i0 + 0]);
        float pyp = __builtin_nontemporal_load(&pts[3 * i0 + 1]);
        float pzp = __builtin_nontemporal_load(&pts[3 * i0 + 2]);
        float dlp = __builtin_nontemporal_load(&dists[i0]) * LOG2E;
        float pxq = __builtin_nontemporal_load(&pts[3 * iq + 0]);
        float pyq = __builtin_nontemporal_load(&pts[3 * iq + 1]);
        float pzq = __builtin_nontemporal_load(&pts[3 * iq + 2]);
        float dlq = __builtin_nontemporal_load(&dists[iq]) * LOG2E;

        float sP = 0.f, p0P = 0.f, p1P = 0.f, p2P = 0.f, p3P = 0.f, penP = 0.f;
        float sQ = 0.f, p0Q = 0.f, p1Q = 0.f, p2Q = 0.f, p3Q = 0.f, penQ = 0.f;
#pragma unroll 4
        for (int e = 0; e < EC; ++e) {
            fvec4 ap = __builtin_nontemporal_load(&act[(size_t)e * (size_t)n + (size_t)i0]);
            fvec4 aq = __builtin_nontemporal_load(&act[(size_t)e * (size_t)n + (size_t)iq]);
            float4 c0 = sp[3 * e + 0];
            float4 c1 = sp[3 * e + 1];
            float4 c2 = sp[3 * e + 2];
            // point P
            {
                float dx = pxp - c0.x, dy = pyp - c0.y, dz = pzp - c0.z;
                float q = (c1.x * dx + c1.w * dy + c2.x * dz) * dx
                        + (c1.y * dy + c2.y * dz) * dy
                        + (c1.z * dz) * dz + c0.w;
                float v = __builtin_amdgcn_exp2f(q);
                sP += v;
                penP += fabsf(v - 0.005f);
                float s0 = __builtin_amdgcn_rcpf(1.0f + __builtin_amdgcn_exp2f(-LOG2E * ap.x));
                float s1 = __builtin_amdgcn_rcpf(1.0f + __builtin_amdgcn_exp2f(-LOG2E * ap.y));
                float s2 = __builtin_amdgcn_rcpf(1.0f + __builtin_amdgcn_exp2f(-LOG2E * ap.z));
                float al = 1.0f - __builtin_amdgcn_exp2f(-fmaxf(ap.w, 0.0f) * dlp);
                p0P += v * s0; p1P += v * s1; p2P += v * s2; p3P += v * al;
            }
            // point Q
            {
                float dx = pxq - c0.x, dy = pyq - c0.y, dz = pzq - c0.z;
                float q = (c1.x * dx + c1.w * dy + c2.x * dz) * dx
                        + (c1.y * dy + c2.y * dz) * dy
                        + (c1.z * dz) * dz + c0.w;
                float v = __builtin_amdgcn_exp2f(q);
                sQ += v;
                penQ += fabsf(v - 0.005f);
                float s0 = __builtin_amdgcn_rcpf(1.0f + __builtin_amdgcn_exp2f(-LOG2E * aq.x));
                float s1 = __builtin_amdgcn_rcpf(1.0f + __builtin_amdgcn_exp2f(-LOG2E * aq.y));
                float s2 = __builtin_amdgcn_rcpf(1.0f + __builtin_amdgcn_exp2f(-LOG2E * aq.z));
                float al = 1.0f - __builtin_amdgcn_exp2f(-fmaxf(aq.w, 0.0f) * dlq);
                p0Q += v * s0; p1Q += v * s1; p2Q += v * s2; p3Q += v * al;
            }
        }
        float rnP = __builtin_amdgcn_rcpf(sP + 0.01f);
        fvec4 oP; oP.x = p0P * rnP; oP.y = p1P * rnP; oP.z = p2P * rnP; oP.w = p3P * rnP;
        __builtin_nontemporal_store(oP, &out[i0]);
        if (v1) {
            float rnQ = __builtin_amdgcn_rcpf(sQ + 0.01f);
            fvec4 oQ; oQ.x = p0Q * rnQ; oQ.y = p1Q * rnQ; oQ.z = p2Q * rnQ; oQ.w = p3Q * rnQ;
            __builtin_nontemporal_store(oQ, &out[i1]);
            pen = penP + penQ;
        } else {
            pen = penP;
        }
    }

    // deterministic per-block reduction: wave butterfly then fixed-order LDS combine
    float w = pen;
#pragma unroll
    for (int off = 32; off >= 1; off >>= 1) w += __shfl_xor(w, off);
    if ((tid & 63) == 0) sred[tid >> 6] = w;
    __syncthreads();
    if (tid == 0) {
        float bp = ((sred[0] + sred[1]) + sred[2]) + sred[3];
        partials[blockIdx.x] = bp;
        __threadfence();  // release: make partial visible device-wide
        unsigned int old = atomicAdd(counter, 1u);
        sdone = (old == (unsigned int)(nblocks - 1)) ? 1 : 0;
    }
    __syncthreads();

    if (sdone) {
        __threadfence();  // acquire: see all partials
        const volatile float* vp = partials;
        double s = 0.0;
        for (int j = tid; j < nblocks; j += BLOCK) s += (double)vp[j];
        rd[tid] = s;
        __syncthreads();
        for (int st = BLOCK / 2; st > 0; st >>= 1) {
            if (tid < st) rd[tid] += rd[tid + st];
            __syncthreads();
        }
        if (tid == 0) *penout = (float)(rd[0] / (double)n);
    }
}

extern "C" void kernel_launch(void* const* d_in, const int* in_sizes, int n_in,
                              void* d_out, int out_size, void* d_ws, size_t ws_size,
                              hipStream_t stream) {
    const float* pts       = (const float*)d_in[0];  // (N,3)
    const float* act       = (const float*)d_in[1];  // (EC,N,4)
    const float* dists     = (const float*)d_in[2];  // (N,1)
    const float* constants = (const float*)d_in[3];  // (EC,1)
    const float* centers   = (const float*)d_in[4];  // (EC,3)
    const float* radii     = (const float*)d_in[5];  // (EC,1)
    const float* rotations = (const float*)d_in[6];  // (EC,3)
    float* out = (float*)d_out;

    int n = in_sizes[0] / 3;
    unsigned int* counter = (unsigned int*)d_ws;
    float* partials = (float*)((char*)d_ws + 256);

    int nblocks = (n + BLOCK * PPT - 1) / (BLOCK * PPT);

    hipMemsetAsync(d_ws, 0, sizeof(unsigned int), stream);
    ldif_fused_kernel<<<nblocks, BLOCK, 0, stream>>>(
        pts, (const fvec4*)act, dists, constants, centers, radii, rotations,
        (fvec4*)out, out + (size_t)4 * n, partials, counter, n, nblocks);
}